// Round 1
// baseline (947.436 us; speedup 1.0000x reference)
//
#include <hip/hip_runtime.h>

typedef __bf16 bf16_t;
typedef bf16_t bf16x8 __attribute__((ext_vector_type(8)));
typedef float f32x4 __attribute__((ext_vector_type(4)));
typedef unsigned short ushortx8 __attribute__((ext_vector_type(8)));

__device__ __forceinline__ unsigned short f2bf(float f) {
  unsigned int u = __float_as_uint(f);
  u += 0x7fffu + ((u >> 16) & 1u);   // round-to-nearest-even
  return (unsigned short)(u >> 16);
}

// ---------------------------------------------------------------------------
// LayerNorm: fp32 [rows x 768] -> bf16 bits [rows x 768]
// one block per row, 256 threads, 3 elems/thread
// ---------------------------------------------------------------------------
__global__ __launch_bounds__(256) void ln_kernel(const float* __restrict__ x,
                                                 const float* __restrict__ g,
                                                 const float* __restrict__ b,
                                                 unsigned short* __restrict__ out) {
  int row = blockIdx.x;
  int t = threadIdx.x;
  const float* xr = x + (size_t)row * 768;
  float v0 = xr[t], v1 = xr[t + 256], v2 = xr[t + 512];
  __shared__ float red[4];
  float s = v0 + v1 + v2;
  for (int o = 32; o > 0; o >>= 1) s += __shfl_down(s, o, 64);
  if ((t & 63) == 0) red[t >> 6] = s;
  __syncthreads();
  float mu = (red[0] + red[1] + red[2] + red[3]) * (1.0f / 768.0f);
  __syncthreads();
  float d0 = v0 - mu, d1 = v1 - mu, d2 = v2 - mu;
  s = d0 * d0 + d1 * d1 + d2 * d2;
  for (int o = 32; o > 0; o >>= 1) s += __shfl_down(s, o, 64);
  if ((t & 63) == 0) red[t >> 6] = s;
  __syncthreads();
  float var = (red[0] + red[1] + red[2] + red[3]) * (1.0f / 768.0f);
  float rs = rsqrtf(var + 1e-6f);
  unsigned short* orow = out + (size_t)row * 768;
  orow[t]       = f2bf(d0 * rs * g[t]       + b[t]);
  orow[t + 256] = f2bf(d1 * rs * g[t + 256] + b[t + 256]);
  orow[t + 512] = f2bf(d2 * rs * g[t + 512] + b[t + 512]);
}

// ---------------------------------------------------------------------------
// Transpose+cast: W fp32 [K x N] -> WT bf16 bits [N x K]
// block (32,8), grid (N/32, K/32)
// ---------------------------------------------------------------------------
__global__ __launch_bounds__(256) void transpose_cast(const float* __restrict__ W,
                                                      unsigned short* __restrict__ WT,
                                                      int K, int N) {
  __shared__ float tile[32][33];
  int n0 = blockIdx.x * 32, k0 = blockIdx.y * 32;
  int tx = threadIdx.x, ty = threadIdx.y;
  for (int i = 0; i < 4; i++)
    tile[ty + i * 8][tx] = W[(size_t)(k0 + ty + i * 8) * N + n0 + tx];
  __syncthreads();
  for (int i = 0; i < 4; i++)
    WT[(size_t)(n0 + ty + i * 8) * K + k0 + tx] = f2bf(tile[tx][ty + i * 8]);
}

// ---------------------------------------------------------------------------
// GEMM: C[M,N] = epi(A[M,K]_bf16 @ BT[N,K]_bf16^T + bias [+ resid])
// EPI 0: bf16 out, cols<768 scaled by 0.125 (QKV with q-scale)
// EPI 1: bf16 out, exact GELU
// EPI 2: fp32 out, + resid fp32
// 128x128 tile, BK=32, 256 threads (4 waves, each 64x64 via 4x4 mfma tiles)
// ---------------------------------------------------------------------------
#define LDP 40  // LDS row pitch in shorts (32 data + 8 pad -> 2-way banks, free)

template <int EPI>
__global__ __launch_bounds__(256) void gemm_kernel(
    const unsigned short* __restrict__ A, const unsigned short* __restrict__ BT,
    const float* __restrict__ bias, const float* __restrict__ resid,
    void* __restrict__ out, int N, int K) {
  __shared__ __align__(16) unsigned short As[128 * LDP];
  __shared__ __align__(16) unsigned short Bs[128 * LDP];
  int t = threadIdx.x;
  int w = t >> 6, lane = t & 63, ln = lane & 15, quad = lane >> 4;
  int wm = w & 1, wn = w >> 1;
  int m0 = blockIdx.y * 128, n0 = blockIdx.x * 128;
  int ar0 = t >> 2, ac0 = (t & 3) * 8;

  f32x4 acc[4][4];
  f32x4 zero = {0.f, 0.f, 0.f, 0.f};
  for (int mi = 0; mi < 4; mi++)
    for (int ni = 0; ni < 4; ni++) acc[mi][ni] = zero;

  int nk = K >> 5;
  for (int kt = 0; kt < nk; kt++) {
    int k0 = kt * 32;
    ushortx8 a0 = *(const ushortx8*)&A[(size_t)(m0 + ar0) * K + k0 + ac0];
    ushortx8 a1 = *(const ushortx8*)&A[(size_t)(m0 + ar0 + 64) * K + k0 + ac0];
    ushortx8 b0 = *(const ushortx8*)&BT[(size_t)(n0 + ar0) * K + k0 + ac0];
    ushortx8 b1 = *(const ushortx8*)&BT[(size_t)(n0 + ar0 + 64) * K + k0 + ac0];
    __syncthreads();
    *(ushortx8*)&As[ar0 * LDP + ac0] = a0;
    *(ushortx8*)&As[(ar0 + 64) * LDP + ac0] = a1;
    *(ushortx8*)&Bs[ar0 * LDP + ac0] = b0;
    *(ushortx8*)&Bs[(ar0 + 64) * LDP + ac0] = b1;
    __syncthreads();
    bf16x8 af[4], bf[4];
    for (int mi = 0; mi < 4; mi++)
      af[mi] = *(const bf16x8*)&As[(wm * 64 + mi * 16 + ln) * LDP + quad * 8];
    for (int ni = 0; ni < 4; ni++)
      bf[ni] = *(const bf16x8*)&Bs[(wn * 64 + ni * 16 + ln) * LDP + quad * 8];
    for (int mi = 0; mi < 4; mi++)
      for (int ni = 0; ni < 4; ni++)
        acc[mi][ni] = __builtin_amdgcn_mfma_f32_16x16x32_bf16(af[mi], bf[ni],
                                                              acc[mi][ni], 0, 0, 0);
  }

  for (int mi = 0; mi < 4; mi++) {
    for (int ni = 0; ni < 4; ni++) {
      int col = n0 + wn * 64 + ni * 16 + ln;
      float bv = bias[col];
      for (int r = 0; r < 4; r++) {
        int row = m0 + wm * 64 + mi * 16 + quad * 4 + r;
        float v = acc[mi][ni][r] + bv;
        if (EPI == 0) {
          if (col < 768) v *= 0.125f;  // q * hd^-0.5
          ((unsigned short*)out)[(size_t)row * N + col] = f2bf(v);
        } else if (EPI == 1) {
          v = 0.5f * v * (1.0f + erff(v * 0.70710678118654752f));
          ((unsigned short*)out)[(size_t)row * N + col] = f2bf(v);
        } else {
          v += resid[(size_t)row * N + col];
          ((float*)out)[(size_t)row * N + col] = v;
        }
      }
    }
  }
}

// ---------------------------------------------------------------------------
// Flash attention: qkv bf16 [8192 x 2304] (q|k|v each 768, q pre-scaled)
// -> o bf16 [8192 x 768] laid out [b,s,h,d]
// block: one (b,h) and 64 queries; loop over 32 K/V-tiles of 64
// ---------------------------------------------------------------------------
__global__ __launch_bounds__(256) void flash_attn(const unsigned short* __restrict__ qkv,
                                                  unsigned short* __restrict__ o) {
  int qt = blockIdx.x;  // 0..31
  int bh = blockIdx.y;  // 0..47
  int b = bh / 12, h = bh % 12;
  int t = threadIdx.x;
  int w = t >> 6, lane = t & 63, ln = lane & 15, quad = lane >> 4;

  __shared__ __align__(16) unsigned short Qs[64 * 72];
  __shared__ __align__(16) unsigned short Ks[64 * 72];
  __shared__ __align__(16) unsigned short Vt[64 * 72];
  __shared__ __align__(16) unsigned short Ps[64 * 72];
  __shared__ float Ss[64 * 68];
  __shared__ float m_s[64], l_s[64], alpha_s[64];
  __shared__ float red_s[64 * 4];

  int qrow0 = b * 2048 + qt * 64;
  for (int c = t; c < 512; c += 256) {
    int r = c >> 3, ch = (c & 7) * 8;
    *(ushortx8*)&Qs[r * 72 + ch] =
        *(const ushortx8*)&qkv[(size_t)(qrow0 + r) * 2304 + h * 64 + ch];
  }
  if (t < 64) { m_s[t] = -1e30f; l_s[t] = 0.0f; }
  f32x4 zero = {0.f, 0.f, 0.f, 0.f};
  f32x4 o_acc[4];
  for (int mi = 0; mi < 4; mi++) o_acc[mi] = zero;

  for (int kt = 0; kt < 32; kt++) {
    __syncthreads();  // prev iter done with Ks/Vt (and iter0: Q load visible)
    int krow0 = b * 2048 + kt * 64;
    for (int c = t; c < 512; c += 256) {
      int r = c >> 3, ch = (c & 7) * 8;
      *(ushortx8*)&Ks[r * 72 + ch] =
          *(const ushortx8*)&qkv[(size_t)(krow0 + r) * 2304 + 768 + h * 64 + ch];
      ushortx8 v8 =
          *(const ushortx8*)&qkv[(size_t)(krow0 + r) * 2304 + 1536 + h * 64 + ch];
      for (int i = 0; i < 8; i++) Vt[(ch + i) * 72 + r] = v8[i];
    }
    __syncthreads();
    // S = Q K^T  (wave w owns key-cols w*16..w*16+16)
    for (int mi = 0; mi < 4; mi++) {
      bf16x8 aq0 = *(const bf16x8*)&Qs[(mi * 16 + ln) * 72 + quad * 8];
      bf16x8 aq1 = *(const bf16x8*)&Qs[(mi * 16 + ln) * 72 + 32 + quad * 8];
      bf16x8 bk0 = *(const bf16x8*)&Ks[(w * 16 + ln) * 72 + quad * 8];
      bf16x8 bk1 = *(const bf16x8*)&Ks[(w * 16 + ln) * 72 + 32 + quad * 8];
      f32x4 sacc = zero;
      sacc = __builtin_amdgcn_mfma_f32_16x16x32_bf16(aq0, bk0, sacc, 0, 0, 0);
      sacc = __builtin_amdgcn_mfma_f32_16x16x32_bf16(aq1, bk1, sacc, 0, 0, 0);
      for (int r = 0; r < 4; r++)
        Ss[(mi * 16 + quad * 4 + r) * 68 + w * 16 + ln] = sacc[r];
    }
    __syncthreads();
    {  // partial row max (4 threads per row)
      int r2 = t >> 2, p = t & 3;
      float pm = -1e30f;
      for (int j = 0; j < 16; j++) pm = fmaxf(pm, Ss[r2 * 68 + p * 16 + j]);
      red_s[r2 * 4 + p] = pm;
    }
    __syncthreads();
    if (t < 64) {
      float tm = fmaxf(fmaxf(red_s[t * 4], red_s[t * 4 + 1]),
                       fmaxf(red_s[t * 4 + 2], red_s[t * 4 + 3]));
      float mo = m_s[t];
      float mn = fmaxf(mo, tm);
      alpha_s[t] = __expf(mo - mn);
      m_s[t] = mn;
    }
    __syncthreads();
    {  // exp + P + partial sums
      int r2 = t >> 2, p = t & 3;
      float mn = m_s[r2];
      float ps = 0.0f;
      for (int j = 0; j < 16; j++) {
        float e = __expf(Ss[r2 * 68 + p * 16 + j] - mn);
        Ps[r2 * 72 + p * 16 + j] = f2bf(e);
        ps += e;
      }
      red_s[r2 * 4 + p] = ps;
    }
    __syncthreads();
    if (t < 64)
      l_s[t] = l_s[t] * alpha_s[t] +
               (red_s[t * 4] + red_s[t * 4 + 1] + red_s[t * 4 + 2] + red_s[t * 4 + 3]);
    // O = O*alpha + P V   (wave w owns dim-cols w*16..w*16+16)
    for (int mi = 0; mi < 4; mi++) {
      for (int r = 0; r < 4; r++) o_acc[mi][r] *= alpha_s[mi * 16 + quad * 4 + r];
      bf16x8 ap0 = *(const bf16x8*)&Ps[(mi * 16 + ln) * 72 + quad * 8];
      bf16x8 ap1 = *(const bf16x8*)&Ps[(mi * 16 + ln) * 72 + 32 + quad * 8];
      bf16x8 bv0 = *(const bf16x8*)&Vt[(w * 16 + ln) * 72 + quad * 8];
      bf16x8 bv1 = *(const bf16x8*)&Vt[(w * 16 + ln) * 72 + 32 + quad * 8];
      o_acc[mi] = __builtin_amdgcn_mfma_f32_16x16x32_bf16(ap0, bv0, o_acc[mi], 0, 0, 0);
      o_acc[mi] = __builtin_amdgcn_mfma_f32_16x16x32_bf16(ap1, bv1, o_acc[mi], 0, 0, 0);
    }
  }
  __syncthreads();
  for (int mi = 0; mi < 4; mi++) {
    for (int r = 0; r < 4; r++) {
      int row = mi * 16 + quad * 4 + r;
      float inv = 1.0f / l_s[row];
      o[(size_t)(qrow0 + row) * 768 + h * 64 + w * 16 + ln] =
          f2bf(o_acc[mi][r] * inv);
    }
  }
}

// ---------------------------------------------------------------------------
extern "C" void kernel_launch(void* const* d_in, const int* in_sizes, int n_in,
                              void* d_out, int out_size, void* d_ws, size_t ws_size,
                              hipStream_t stream) {
  const float* hidden = (const float*)d_in[0];
  const float* ln1_g  = (const float*)d_in[1];
  const float* ln1_b  = (const float*)d_in[2];
  const float* w_qkv  = (const float*)d_in[3];
  const float* b_qkv  = (const float*)d_in[4];
  const float* w_attn = (const float*)d_in[5];
  const float* b_attn = (const float*)d_in[6];
  const float* ln2_g  = (const float*)d_in[7];
  const float* ln2_b  = (const float*)d_in[8];
  const float* w_in   = (const float*)d_in[9];
  const float* b_in   = (const float*)d_in[10];
  const float* w_out  = (const float*)d_in[11];
  const float* b_out  = (const float*)d_in[12];
  float* out = (float*)d_out;

  char* ws = (char*)d_ws;
  // ws layout (bytes):
  unsigned short* wqkvT  = (unsigned short*)(ws + 0);         // 2304x768 bf16
  unsigned short* wattnT = (unsigned short*)(ws + 3538944);   //  768x768
  unsigned short* winT   = (unsigned short*)(ws + 4718592);   // 3072x768
  unsigned short* woutT  = (unsigned short*)(ws + 9437184);   //  768x3072
  unsigned short* bufX   = (unsigned short*)(ws + 14155776);  // 8192x768 bf16 (ln1/O/ln2)
  unsigned short* bufBig = (unsigned short*)(ws + 26738688);  // 8192x3072 bf16 (qkv/ffn1)

  dim3 tb(32, 8);
  transpose_cast<<<dim3(2304 / 32, 768 / 32), tb, 0, stream>>>(w_qkv, wqkvT, 768, 2304);
  transpose_cast<<<dim3(768 / 32, 768 / 32), tb, 0, stream>>>(w_attn, wattnT, 768, 768);
  transpose_cast<<<dim3(3072 / 32, 768 / 32), tb, 0, stream>>>(w_in, winT, 768, 3072);
  transpose_cast<<<dim3(768 / 32, 3072 / 32), tb, 0, stream>>>(w_out, woutT, 3072, 768);

  // LN1 -> bufX
  ln_kernel<<<8192, 256, 0, stream>>>(hidden, ln1_g, ln1_b, bufX);
  // QKV = ln1 @ w_qkv + b_qkv (q scaled) -> bufBig [8192x2304] bf16
  gemm_kernel<0><<<dim3(18, 64), 256, 0, stream>>>(bufX, wqkvT, b_qkv, nullptr,
                                                   (void*)bufBig, 2304, 768);
  // attention -> bufX [8192x768] bf16
  flash_attn<<<dim3(32, 48), 256, 0, stream>>>(bufBig, bufX);
  // h = hidden + O @ w_attn + b_attn -> d_out fp32
  gemm_kernel<2><<<dim3(6, 64), 256, 0, stream>>>(bufX, wattnT, b_attn, hidden,
                                                  (void*)out, 768, 768);
  // LN2 -> bufX
  ln_kernel<<<8192, 256, 0, stream>>>(out, ln2_g, ln2_b, bufX);
  // FFN1 = gelu(ln2 @ w_in + b_in) -> bufBig [8192x3072] bf16
  gemm_kernel<1><<<dim3(24, 64), 256, 0, stream>>>(bufX, winT, b_in, nullptr,
                                                   (void*)bufBig, 3072, 768);
  // out = h + ffn1 @ w_out + b_out -> d_out fp32 (in-place residual)
  gemm_kernel<2><<<dim3(6, 64), 256, 0, stream>>>(bufBig, woutT, b_out, out,
                                                  (void*)out, 768, 3072);
}

// Round 4
// 654.725 us; speedup vs baseline: 1.4471x; 1.4471x over previous
//
#include <hip/hip_runtime.h>

typedef __bf16 bf16_t;
typedef bf16_t bf16x8 __attribute__((ext_vector_type(8)));
typedef float f32x4 __attribute__((ext_vector_type(4)));
typedef unsigned short ushortx8 __attribute__((ext_vector_type(8)));

__device__ __forceinline__ unsigned short f2bf(float f) {
  unsigned int u = __float_as_uint(f);
  u += 0x7fffu + ((u >> 16) & 1u);   // round-to-nearest-even
  return (unsigned short)(u >> 16);
}

// ---------------------------------------------------------------------------
// LayerNorm: fp32 [rows x 768] -> bf16 bits [rows x 768]
// ---------------------------------------------------------------------------
__global__ __launch_bounds__(256) void ln_kernel(const float* __restrict__ x,
                                                 const float* __restrict__ g,
                                                 const float* __restrict__ b,
                                                 unsigned short* __restrict__ out) {
  int row = blockIdx.x;
  int t = threadIdx.x;
  const float* xr = x + (size_t)row * 768;
  float v0 = xr[t], v1 = xr[t + 256], v2 = xr[t + 512];
  __shared__ float red[4];
  float s = v0 + v1 + v2;
  for (int o = 32; o > 0; o >>= 1) s += __shfl_down(s, o, 64);
  if ((t & 63) == 0) red[t >> 6] = s;
  __syncthreads();
  float mu = (red[0] + red[1] + red[2] + red[3]) * (1.0f / 768.0f);
  __syncthreads();
  float d0 = v0 - mu, d1 = v1 - mu, d2 = v2 - mu;
  s = d0 * d0 + d1 * d1 + d2 * d2;
  for (int o = 32; o > 0; o >>= 1) s += __shfl_down(s, o, 64);
  if ((t & 63) == 0) red[t >> 6] = s;
  __syncthreads();
  float var = (red[0] + red[1] + red[2] + red[3]) * (1.0f / 768.0f);
  float rs = rsqrtf(var + 1e-6f);
  unsigned short* orow = out + (size_t)row * 768;
  orow[t]       = f2bf(d0 * rs * g[t]       + b[t]);
  orow[t + 256] = f2bf(d1 * rs * g[t + 256] + b[t + 256]);
  orow[t + 512] = f2bf(d2 * rs * g[t + 512] + b[t + 512]);
}

// ---------------------------------------------------------------------------
// Transpose+cast: W fp32 [K x N] -> WT bf16 bits [N x K]
// ---------------------------------------------------------------------------
__global__ __launch_bounds__(256) void transpose_cast(const float* __restrict__ W,
                                                      unsigned short* __restrict__ WT,
                                                      int K, int N) {
  __shared__ float tile[32][33];
  int n0 = blockIdx.x * 32, k0 = blockIdx.y * 32;
  int tx = threadIdx.x, ty = threadIdx.y;
  for (int i = 0; i < 4; i++)
    tile[ty + i * 8][tx] = W[(size_t)(k0 + ty + i * 8) * N + n0 + tx];
  __syncthreads();
  for (int i = 0; i < 4; i++)
    WT[(size_t)(n0 + ty + i * 8) * K + k0 + tx] = f2bf(tile[tx][ty + i * 8]);
}

// ---------------------------------------------------------------------------
// GEMM body: C[M,N] = epi(A[M,K]_bf16 @ BT[N,K]_bf16^T + bias [+ resid])
// Register->LDS staging, pitch 32 (2-way bank alias = free), 128x128 tile,
// BK=32, 4 waves x (4x4) 16x16x32 mfma.
// EPI 0: bf16 out, cols<768 scaled 0.125 (QKV q-scale) — LDS-staged stores,
//        barrier-fenced (unfenced in-wave LDS round-trip miscompiled: TBAA
//        lets the vector ds_read hoist above the scalar ds_writes).
// EPI 1: bf16 out, exact GELU — same LDS-staged stores.
// EPI 2: fp32 out, + resid — direct scalar stores (64B segments; proven fast
//        and correct in round 1).
// ---------------------------------------------------------------------------
template <int EPI>
__device__ __forceinline__ void gemm_body(const unsigned short* __restrict__ A,
                                          const unsigned short* __restrict__ BT,
                                          const float* __restrict__ bias,
                                          const float* resid,
                                          void* out, int N, int K) {
  __shared__ __align__(16) unsigned short smem[128 * 64];  // 16 KB: As | Bs
  unsigned short* As = smem;
  unsigned short* Bs = smem + 4096;

  int t = threadIdx.x;
  int w = t >> 6, lane = t & 63, ln = lane & 15, quad = lane >> 4;
  int wm = w & 1, wn = w >> 1;
  int m0 = blockIdx.y * 128, n0 = blockIdx.x * 128;
  int ar0 = t >> 2, ac0 = (t & 3) * 8;

  f32x4 acc[4][4];
  f32x4 zero = {0.f, 0.f, 0.f, 0.f};
  for (int mi = 0; mi < 4; mi++)
    for (int ni = 0; ni < 4; ni++) acc[mi][ni] = zero;

  int nk = K >> 5;
  for (int kt = 0; kt < nk; kt++) {
    int k0 = kt * 32;
    ushortx8 a0 = *(const ushortx8*)&A[(size_t)(m0 + ar0) * K + k0 + ac0];
    ushortx8 a1 = *(const ushortx8*)&A[(size_t)(m0 + ar0 + 64) * K + k0 + ac0];
    ushortx8 b0 = *(const ushortx8*)&BT[(size_t)(n0 + ar0) * K + k0 + ac0];
    ushortx8 b1 = *(const ushortx8*)&BT[(size_t)(n0 + ar0 + 64) * K + k0 + ac0];
    __syncthreads();  // previous iter's ds_reads done before LDS overwrite
    *(ushortx8*)&As[ar0 * 32 + ac0] = a0;
    *(ushortx8*)&As[(ar0 + 64) * 32 + ac0] = a1;
    *(ushortx8*)&Bs[ar0 * 32 + ac0] = b0;
    *(ushortx8*)&Bs[(ar0 + 64) * 32 + ac0] = b1;
    __syncthreads();
    bf16x8 af[4], bf[4];
    for (int mi = 0; mi < 4; mi++)
      af[mi] = *(const bf16x8*)&As[(wm * 64 + mi * 16 + ln) * 32 + quad * 8];
    for (int ni = 0; ni < 4; ni++)
      bf[ni] = *(const bf16x8*)&Bs[(wn * 64 + ni * 16 + ln) * 32 + quad * 8];
    for (int mi = 0; mi < 4; mi++)
      for (int ni = 0; ni < 4; ni++)
        acc[mi][ni] = __builtin_amdgcn_mfma_f32_16x16x32_bf16(af[mi], bf[ni],
                                                              acc[mi][ni], 0, 0, 0);
  }

  if (EPI == 2) {
    // direct scalar stores (round-1 proven)
    float* outp = (float*)out;
    for (int mi = 0; mi < 4; mi++) {
      for (int ni = 0; ni < 4; ni++) {
        int col = n0 + wn * 64 + ni * 16 + ln;
        float bv = bias[col];
        for (int r = 0; r < 4; r++) {
          int row = m0 + wm * 64 + mi * 16 + quad * 4 + r;
          float v = acc[mi][ni][r] + bv;
          v += resid[(size_t)row * N + col];
          outp[(size_t)row * N + col] = v;
        }
      }
    }
  } else {
    __syncthreads();  // all waves done with As/Bs; reuse as epilogue scratch
    unsigned short* Cs16 = smem + w * 1024;  // 2 KB per wave (16 rows x 64)
    unsigned short* outp = (unsigned short*)out;
    for (int mi = 0; mi < 4; mi++) {
      for (int ni = 0; ni < 4; ni++) {
        int col = n0 + wn * 64 + ni * 16 + ln;
        float bv = bias[col];
        for (int r = 0; r < 4; r++) {
          float v = acc[mi][ni][r] + bv;
          if (EPI == 0) {
            if (col < 768) v *= 0.125f;  // q * hd^-0.5
          } else {
            v = 0.5f * v * (1.0f + erff(v * 0.70710678118654752f));
          }
          Cs16[(quad * 4 + r) * 64 + ni * 16 + ln] = f2bf(v);
        }
      }
      __syncthreads();  // fence: scalar ds_writes visible before vector ds_read
      for (int j = 0; j < 2; j++) {
        int rrow = j * 8 + (lane >> 3);
        int ch = (lane & 7) * 8;
        ushortx8 pv = *(const ushortx8*)&Cs16[rrow * 64 + ch];
        *(ushortx8*)&outp[(size_t)(m0 + wm * 64 + mi * 16 + rrow) * N +
                          n0 + wn * 64 + ch] = pv;
      }
      __syncthreads();  // reads done before next slab overwrites scratch
    }
  }
}

// distinct kernel names for rocprof attribution
__global__ __launch_bounds__(256) void gemm_qkv(const unsigned short* A,
    const unsigned short* BT, const float* bias, void* out, int N, int K) {
  gemm_body<0>(A, BT, bias, nullptr, out, N, K);
}
__global__ __launch_bounds__(256) void gemm_attnout(const unsigned short* A,
    const unsigned short* BT, const float* bias, const float* resid, void* out,
    int N, int K) {
  gemm_body<2>(A, BT, bias, resid, out, N, K);
}
__global__ __launch_bounds__(256) void gemm_ffn1(const unsigned short* A,
    const unsigned short* BT, const float* bias, void* out, int N, int K) {
  gemm_body<1>(A, BT, bias, nullptr, out, N, K);
}
__global__ __launch_bounds__(256) void gemm_ffn2(const unsigned short* A,
    const unsigned short* BT, const float* bias, const float* resid, void* out,
    int N, int K) {
  gemm_body<2>(A, BT, bias, resid, out, N, K);
}

// ---------------------------------------------------------------------------
// Flash attention: qkv bf16 [8192 x 2304] (q|k|v each 768, q pre-scaled)
// -> o bf16 [8192 x 768]
// ---------------------------------------------------------------------------
__global__ __launch_bounds__(256) void flash_attn(const unsigned short* __restrict__ qkv,
                                                  unsigned short* __restrict__ o) {
  int qt = blockIdx.x;  // 0..31
  int bh = blockIdx.y;  // 0..47
  int b = bh / 12, h = bh % 12;
  int t = threadIdx.x;
  int w = t >> 6, lane = t & 63, ln = lane & 15, quad = lane >> 4;

  __shared__ __align__(16) unsigned short Qs[64 * 72];
  __shared__ __align__(16) unsigned short Ks[64 * 72];
  __shared__ __align__(16) unsigned short Vt[64 * 72];
  __shared__ __align__(16) unsigned short Ps[64 * 72];
  __shared__ float Ss[64 * 68];
  __shared__ float m_s[64], l_s[64], alpha_s[64];
  __shared__ float red_s[64 * 4];

  int qrow0 = b * 2048 + qt * 64;
  for (int c = t; c < 512; c += 256) {
    int r = c >> 3, ch = (c & 7) * 8;
    *(ushortx8*)&Qs[r * 72 + ch] =
        *(const ushortx8*)&qkv[(size_t)(qrow0 + r) * 2304 + h * 64 + ch];
  }
  if (t < 64) { m_s[t] = -1e30f; l_s[t] = 0.0f; }
  f32x4 zero = {0.f, 0.f, 0.f, 0.f};
  f32x4 o_acc[4];
  for (int mi = 0; mi < 4; mi++) o_acc[mi] = zero;

  for (int kt = 0; kt < 32; kt++) {
    __syncthreads();
    int krow0 = b * 2048 + kt * 64;
    for (int c = t; c < 512; c += 256) {
      int r = c >> 3, ch = (c & 7) * 8;
      *(ushortx8*)&Ks[r * 72 + ch] =
          *(const ushortx8*)&qkv[(size_t)(krow0 + r) * 2304 + 768 + h * 64 + ch];
      ushortx8 v8 =
          *(const ushortx8*)&qkv[(size_t)(krow0 + r) * 2304 + 1536 + h * 64 + ch];
      for (int i = 0; i < 8; i++) Vt[(ch + i) * 72 + r] = v8[i];
    }
    __syncthreads();
    for (int mi = 0; mi < 4; mi++) {
      bf16x8 aq0 = *(const bf16x8*)&Qs[(mi * 16 + ln) * 72 + quad * 8];
      bf16x8 aq1 = *(const bf16x8*)&Qs[(mi * 16 + ln) * 72 + 32 + quad * 8];
      bf16x8 bk0 = *(const bf16x8*)&Ks[(w * 16 + ln) * 72 + quad * 8];
      bf16x8 bk1 = *(const bf16x8*)&Ks[(w * 16 + ln) * 72 + 32 + quad * 8];
      f32x4 sacc = zero;
      sacc = __builtin_amdgcn_mfma_f32_16x16x32_bf16(aq0, bk0, sacc, 0, 0, 0);
      sacc = __builtin_amdgcn_mfma_f32_16x16x32_bf16(aq1, bk1, sacc, 0, 0, 0);
      for (int r = 0; r < 4; r++)
        Ss[(mi * 16 + quad * 4 + r) * 68 + w * 16 + ln] = sacc[r];
    }
    __syncthreads();
    {
      int r2 = t >> 2, p = t & 3;
      float pm = -1e30f;
      for (int j = 0; j < 16; j++) pm = fmaxf(pm, Ss[r2 * 68 + p * 16 + j]);
      red_s[r2 * 4 + p] = pm;
    }
    __syncthreads();
    if (t < 64) {
      float tm = fmaxf(fmaxf(red_s[t * 4], red_s[t * 4 + 1]),
                       fmaxf(red_s[t * 4 + 2], red_s[t * 4 + 3]));
      float mo = m_s[t];
      float mn = fmaxf(mo, tm);
      alpha_s[t] = __expf(mo - mn);
      m_s[t] = mn;
    }
    __syncthreads();
    {
      int r2 = t >> 2, p = t & 3;
      float mn = m_s[r2];
      float ps = 0.0f;
      for (int j = 0; j < 16; j++) {
        float e = __expf(Ss[r2 * 68 + p * 16 + j] - mn);
        Ps[r2 * 72 + p * 16 + j] = f2bf(e);
        ps += e;
      }
      red_s[r2 * 4 + p] = ps;
    }
    __syncthreads();
    if (t < 64)
      l_s[t] = l_s[t] * alpha_s[t] +
               (red_s[t * 4] + red_s[t * 4 + 1] + red_s[t * 4 + 2] + red_s[t * 4 + 3]);
    for (int mi = 0; mi < 4; mi++) {
      for (int r = 0; r < 4; r++) o_acc[mi][r] *= alpha_s[mi * 16 + quad * 4 + r];
      bf16x8 ap0 = *(const bf16x8*)&Ps[(mi * 16 + ln) * 72 + quad * 8];
      bf16x8 ap1 = *(const bf16x8*)&Ps[(mi * 16 + ln) * 72 + 32 + quad * 8];
      bf16x8 bv0 = *(const bf16x8*)&Vt[(w * 16 + ln) * 72 + quad * 8];
      bf16x8 bv1 = *(const bf16x8*)&Vt[(w * 16 + ln) * 72 + 32 + quad * 8];
      o_acc[mi] = __builtin_amdgcn_mfma_f32_16x16x32_bf16(ap0, bv0, o_acc[mi], 0, 0, 0);
      o_acc[mi] = __builtin_amdgcn_mfma_f32_16x16x32_bf16(ap1, bv1, o_acc[mi], 0, 0, 0);
    }
  }
  __syncthreads();
  for (int mi = 0; mi < 4; mi++) {
    for (int r = 0; r < 4; r++) {
      int row = mi * 16 + quad * 4 + r;
      float inv = 1.0f / l_s[row];
      o[(size_t)(qrow0 + row) * 768 + h * 64 + w * 16 + ln] =
          f2bf(o_acc[mi][r] * inv);
    }
  }
}

// ---------------------------------------------------------------------------
extern "C" void kernel_launch(void* const* d_in, const int* in_sizes, int n_in,
                              void* d_out, int out_size, void* d_ws, size_t ws_size,
                              hipStream_t stream) {
  const float* hidden = (const float*)d_in[0];
  const float* ln1_g  = (const float*)d_in[1];
  const float* ln1_b  = (const float*)d_in[2];
  const float* w_qkv  = (const float*)d_in[3];
  const float* b_qkv  = (const float*)d_in[4];
  const float* w_attn = (const float*)d_in[5];
  const float* b_attn = (const float*)d_in[6];
  const float* ln2_g  = (const float*)d_in[7];
  const float* ln2_b  = (const float*)d_in[8];
  const float* w_in   = (const float*)d_in[9];
  const float* b_in   = (const float*)d_in[10];
  const float* w_out  = (const float*)d_in[11];
  const float* b_out  = (const float*)d_in[12];
  float* out = (float*)d_out;

  char* ws = (char*)d_ws;
  unsigned short* wqkvT  = (unsigned short*)(ws + 0);         // 2304x768 bf16
  unsigned short* wattnT = (unsigned short*)(ws + 3538944);   //  768x768
  unsigned short* winT   = (unsigned short*)(ws + 4718592);   // 3072x768
  unsigned short* woutT  = (unsigned short*)(ws + 9437184);   //  768x3072
  unsigned short* bufX   = (unsigned short*)(ws + 14155776);  // 8192x768 bf16
  unsigned short* bufBig = (unsigned short*)(ws + 26738688);  // 8192x3072 bf16

  dim3 tb(32, 8);
  transpose_cast<<<dim3(2304 / 32, 768 / 32), tb, 0, stream>>>(w_qkv, wqkvT, 768, 2304);
  transpose_cast<<<dim3(768 / 32, 768 / 32), tb, 0, stream>>>(w_attn, wattnT, 768, 768);
  transpose_cast<<<dim3(3072 / 32, 768 / 32), tb, 0, stream>>>(w_in, winT, 768, 3072);
  transpose_cast<<<dim3(768 / 32, 3072 / 32), tb, 0, stream>>>(w_out, woutT, 3072, 768);

  ln_kernel<<<8192, 256, 0, stream>>>(hidden, ln1_g, ln1_b, bufX);
  gemm_qkv<<<dim3(18, 64), 256, 0, stream>>>(bufX, wqkvT, b_qkv, (void*)bufBig,
                                             2304, 768);
  flash_attn<<<dim3(32, 48), 256, 0, stream>>>(bufBig, bufX);
  gemm_attnout<<<dim3(6, 64), 256, 0, stream>>>(bufX, wattnT, b_attn, hidden,
                                                (void*)out, 768, 768);
  ln_kernel<<<8192, 256, 0, stream>>>(out, ln2_g, ln2_b, bufX);
  gemm_ffn1<<<dim3(24, 64), 256, 0, stream>>>(bufX, winT, b_in, (void*)bufBig,
                                              3072, 768);
  gemm_ffn2<<<dim3(6, 64), 256, 0, stream>>>(bufBig, woutT, b_out, out,
                                             (void*)out, 768, 3072);
}

// Round 5
// 554.010 us; speedup vs baseline: 1.7101x; 1.1818x over previous
//
#include <hip/hip_runtime.h>

typedef __bf16 bf16_t;
typedef bf16_t bf16x8 __attribute__((ext_vector_type(8)));
typedef float f32x4 __attribute__((ext_vector_type(4)));
typedef unsigned short ushortx8 __attribute__((ext_vector_type(8)));
typedef unsigned short ushortx4 __attribute__((ext_vector_type(4)));

union U8 { ushortx4 h[2]; bf16x8 b; ushortx8 u; };

__device__ __forceinline__ unsigned short f2bf(float f) {
  unsigned int u = __float_as_uint(f);
  u += 0x7fffu + ((u >> 16) & 1u);   // round-to-nearest-even
  return (unsigned short)(u >> 16);
}

// ---------------------------------------------------------------------------
// LayerNorm: fp32 [rows x 768] -> bf16 bits [rows x 768]
// ---------------------------------------------------------------------------
__global__ __launch_bounds__(256) void ln_kernel(const float* __restrict__ x,
                                                 const float* __restrict__ g,
                                                 const float* __restrict__ b,
                                                 unsigned short* __restrict__ out) {
  int row = blockIdx.x;
  int t = threadIdx.x;
  const float* xr = x + (size_t)row * 768;
  float v0 = xr[t], v1 = xr[t + 256], v2 = xr[t + 512];
  __shared__ float red[4];
  float s = v0 + v1 + v2;
  for (int o = 32; o > 0; o >>= 1) s += __shfl_down(s, o, 64);
  if ((t & 63) == 0) red[t >> 6] = s;
  __syncthreads();
  float mu = (red[0] + red[1] + red[2] + red[3]) * (1.0f / 768.0f);
  __syncthreads();
  float d0 = v0 - mu, d1 = v1 - mu, d2 = v2 - mu;
  s = d0 * d0 + d1 * d1 + d2 * d2;
  for (int o = 32; o > 0; o >>= 1) s += __shfl_down(s, o, 64);
  if ((t & 63) == 0) red[t >> 6] = s;
  __syncthreads();
  float var = (red[0] + red[1] + red[2] + red[3]) * (1.0f / 768.0f);
  float rs = rsqrtf(var + 1e-6f);
  unsigned short* orow = out + (size_t)row * 768;
  orow[t]       = f2bf(d0 * rs * g[t]       + b[t]);
  orow[t + 256] = f2bf(d1 * rs * g[t + 256] + b[t + 256]);
  orow[t + 512] = f2bf(d2 * rs * g[t + 512] + b[t + 512]);
}

// ---------------------------------------------------------------------------
// Transpose+cast: W fp32 [K x N] -> WT bf16 bits [N x K]
// ---------------------------------------------------------------------------
__global__ __launch_bounds__(256) void transpose_cast(const float* __restrict__ W,
                                                      unsigned short* __restrict__ WT,
                                                      int K, int N) {
  __shared__ float tile[32][33];
  int n0 = blockIdx.x * 32, k0 = blockIdx.y * 32;
  int tx = threadIdx.x, ty = threadIdx.y;
  for (int i = 0; i < 4; i++)
    tile[ty + i * 8][tx] = W[(size_t)(k0 + ty + i * 8) * N + n0 + tx];
  __syncthreads();
  for (int i = 0; i < 4; i++)
    WT[(size_t)(n0 + ty + i * 8) * K + k0 + tx] = f2bf(tile[tx][ty + i * 8]);
}

// ---------------------------------------------------------------------------
// GEMM body: C[M,N] = epi(A[M,K]_bf16 @ BT[N,K]_bf16^T + bias [+ resid])
// 128x128 tile, BK=32, 4 waves x (4x4) 16x16x32 mfma, pitch-32 LDS staging.
// EPI 0: QKV. Q/K cols (<1536): bf16 out at row-stride `os` (=1536), q cols
//        scaled 0.125. V cols (>=1536): written TRANSPOSED to vt as
//        [b*768 + (h*64+d)][s] (bf16) — feeds flash_attn's V^T staging.
// EPI 1: bf16 out, exact GELU, stride N.
// EPI 2: fp32 out, + resid, direct scalar stores (round-1 proven).
// bf16 epilogues round-trip through LDS with barrier fences (TBAA hazard:
// unfenced scalar-write -> vector-read miscompiles).
// ---------------------------------------------------------------------------
template <int EPI>
__device__ __forceinline__ void gemm_body(const unsigned short* __restrict__ A,
                                          const unsigned short* __restrict__ BT,
                                          const float* __restrict__ bias,
                                          const float* resid,
                                          void* out, unsigned short* vt, int os,
                                          int N, int K) {
  __shared__ __align__(16) unsigned short smem[128 * 64];  // 16 KB: As | Bs
  unsigned short* As = smem;
  unsigned short* Bs = smem + 4096;

  int t = threadIdx.x;
  int w = t >> 6, lane = t & 63, ln = lane & 15, quad = lane >> 4;
  int wm = w & 1, wn = w >> 1;
  int m0 = blockIdx.y * 128, n0 = blockIdx.x * 128;
  int ar0 = t >> 2, ac0 = (t & 3) * 8;

  f32x4 acc[4][4];
  f32x4 zero = {0.f, 0.f, 0.f, 0.f};
  for (int mi = 0; mi < 4; mi++)
    for (int ni = 0; ni < 4; ni++) acc[mi][ni] = zero;

  int nk = K >> 5;
  for (int kt = 0; kt < nk; kt++) {
    int k0 = kt * 32;
    ushortx8 a0 = *(const ushortx8*)&A[(size_t)(m0 + ar0) * K + k0 + ac0];
    ushortx8 a1 = *(const ushortx8*)&A[(size_t)(m0 + ar0 + 64) * K + k0 + ac0];
    ushortx8 b0 = *(const ushortx8*)&BT[(size_t)(n0 + ar0) * K + k0 + ac0];
    ushortx8 b1 = *(const ushortx8*)&BT[(size_t)(n0 + ar0 + 64) * K + k0 + ac0];
    __syncthreads();
    *(ushortx8*)&As[ar0 * 32 + ac0] = a0;
    *(ushortx8*)&As[(ar0 + 64) * 32 + ac0] = a1;
    *(ushortx8*)&Bs[ar0 * 32 + ac0] = b0;
    *(ushortx8*)&Bs[(ar0 + 64) * 32 + ac0] = b1;
    __syncthreads();
    bf16x8 af[4], bf[4];
    for (int mi = 0; mi < 4; mi++)
      af[mi] = *(const bf16x8*)&As[(wm * 64 + mi * 16 + ln) * 32 + quad * 8];
    for (int ni = 0; ni < 4; ni++)
      bf[ni] = *(const bf16x8*)&Bs[(wn * 64 + ni * 16 + ln) * 32 + quad * 8];
    for (int mi = 0; mi < 4; mi++)
      for (int ni = 0; ni < 4; ni++)
        acc[mi][ni] = __builtin_amdgcn_mfma_f32_16x16x32_bf16(af[mi], bf[ni],
                                                              acc[mi][ni], 0, 0, 0);
  }

  if (EPI == 2) {
    float* outp = (float*)out;
    for (int mi = 0; mi < 4; mi++) {
      for (int ni = 0; ni < 4; ni++) {
        int col = n0 + wn * 64 + ni * 16 + ln;
        float bv = bias[col];
        for (int r = 0; r < 4; r++) {
          int row = m0 + wm * 64 + mi * 16 + quad * 4 + r;
          float v = acc[mi][ni][r] + bv;
          v += resid[(size_t)row * N + col];
          outp[(size_t)row * N + col] = v;
        }
      }
    }
  } else {
    __syncthreads();
    unsigned short* Cs16 = smem + w * 1024;  // 2 KB per wave (16 rows x 64)
    unsigned short* outp = (unsigned short*)out;
    for (int mi = 0; mi < 4; mi++) {
      for (int ni = 0; ni < 4; ni++) {
        int col = n0 + wn * 64 + ni * 16 + ln;
        float bv = bias[col];
        for (int r = 0; r < 4; r++) {
          float v = acc[mi][ni][r] + bv;
          if (EPI == 0) {
            if (col < 768) v *= 0.125f;  // q * hd^-0.5
          } else {
            v = 0.5f * v * (1.0f + erff(v * 0.70710678118654752f));
          }
          Cs16[(quad * 4 + r) * 64 + ni * 16 + ln] = f2bf(v);
        }
      }
      __syncthreads();  // fence: scalar ds_writes visible before reads
      if (EPI == 0 && n0 >= 1536) {
        // V^T path: lane <-> column; 16 s-values contiguous per store
        int c = n0 - 1536 + wn * 64 + lane;  // h*64+d, 0..767
        int s0 = m0 + wm * 64 + mi * 16;
        int bb = s0 >> 11, sl = s0 & 2047;
        ushortx8 lo, hi;
        for (int r = 0; r < 8; r++) lo[r] = Cs16[r * 64 + lane];
        for (int r = 0; r < 8; r++) hi[r] = Cs16[(8 + r) * 64 + lane];
        size_t vbase = ((size_t)(bb * 768 + c)) * 2048 + sl;
        *(ushortx8*)&vt[vbase] = lo;
        *(ushortx8*)&vt[vbase + 8] = hi;
      } else {
        int OS = (EPI == 0) ? os : N;
        for (int j = 0; j < 2; j++) {
          int rrow = j * 8 + (lane >> 3);
          int ch = (lane & 7) * 8;
          ushortx8 pv = *(const ushortx8*)&Cs16[rrow * 64 + ch];
          *(ushortx8*)&outp[(size_t)(m0 + wm * 64 + mi * 16 + rrow) * OS +
                            n0 + wn * 64 + ch] = pv;
        }
      }
      __syncthreads();  // reads done before next slab overwrites scratch
    }
  }
}

__global__ __launch_bounds__(256) void gemm_qkv(const unsigned short* A,
    const unsigned short* BT, const float* bias, void* out, unsigned short* vt,
    int N, int K) {
  gemm_body<0>(A, BT, bias, nullptr, out, vt, 1536, N, K);
}
__global__ __launch_bounds__(256) void gemm_attnout(const unsigned short* A,
    const unsigned short* BT, const float* bias, const float* resid, void* out,
    int N, int K) {
  gemm_body<2>(A, BT, bias, resid, out, nullptr, N, N, K);
}
__global__ __launch_bounds__(256) void gemm_ffn1(const unsigned short* A,
    const unsigned short* BT, const float* bias, void* out, int N, int K) {
  gemm_body<1>(A, BT, bias, nullptr, out, nullptr, N, N, K);
}
__global__ __launch_bounds__(256) void gemm_ffn2(const unsigned short* A,
    const unsigned short* BT, const float* bias, const float* resid, void* out,
    int N, int K) {
  gemm_body<2>(A, BT, bias, resid, out, nullptr, N, N, K);
}

// ---------------------------------------------------------------------------
// Flash attention v2 — register softmax.
// qk: bf16 [8192 x 1536] (q|k, q pre-scaled); v_t: bf16 [48*64 x 2048] (V^T).
// Block: 128 q-rows x (b,h); 4 waves, wave owns 32 rows x all 64 keys/iter.
// Softmax entirely in registers (shfl_xor over the 16-lane col group);
// P -> A-frag via per-wave LDS (pitch 68, barrier-fenced).
// ---------------------------------------------------------------------------
__global__ __launch_bounds__(256, 3) void flash_attn(
    const unsigned short* __restrict__ qk, const unsigned short* __restrict__ v_t,
    unsigned short* __restrict__ o) {
  int qt = blockIdx.x;  // 0..15
  int bh = blockIdx.y;  // 0..47
  int b = bh / 12, h = bh % 12;
  int t = threadIdx.x;
  int w = t >> 6, lane = t & 63, ln = lane & 15, quad = lane >> 4;

  __shared__ __align__(16) unsigned short Ks[64 * 72];
  __shared__ __align__(16) unsigned short Vt[64 * 72];
  __shared__ __align__(16) unsigned short Pws_all[4][32 * 68];
  unsigned short* Pws = Pws_all[w];

  int qrow0 = b * 2048 + qt * 128;

  // Q A-frags in registers (once)
  bf16x8 qf[2][2];
  for (int mi = 0; mi < 2; mi++)
    for (int kh = 0; kh < 2; kh++)
      qf[mi][kh] = *(const bf16x8*)&qk[(size_t)(qrow0 + w * 32 + mi * 16 + ln) * 1536 +
                                      h * 64 + kh * 32 + quad * 8];

  f32x4 zero = {0.f, 0.f, 0.f, 0.f};
  f32x4 o_acc[2][4];
  for (int mi = 0; mi < 2; mi++)
    for (int ni = 0; ni < 4; ni++) o_acc[mi][ni] = zero;
  float mrow[2][4], lrow[2][4];
  for (int mi = 0; mi < 2; mi++)
    for (int r = 0; r < 4; r++) { mrow[mi][r] = -1e30f; lrow[mi][r] = 0.0f; }

  int sr = t >> 3, sc = (t & 7) * 8;  // staging: 32 rows x 8 chunks per pass
  for (int kt = 0; kt < 32; kt++) {
    int krow0 = b * 2048 + kt * 64;
    ushortx8 kreg[2], vreg[2];
    for (int p = 0; p < 2; p++) {
      int r = p * 32 + sr;
      kreg[p] = *(const ushortx8*)&qk[(size_t)(krow0 + r) * 1536 + 768 + h * 64 + sc];
      vreg[p] = *(const ushortx8*)&v_t[(size_t)(bh * 64 + r) * 2048 + kt * 64 + sc];
    }
    __syncthreads();  // prev iter's frag reads done
    for (int p = 0; p < 2; p++) {
      int r = p * 32 + sr;
      *(ushortx8*)&Ks[r * 72 + sc] = kreg[p];
      *(ushortx8*)&Vt[r * 72 + sc] = vreg[p];
    }
    __syncthreads();

    // S = Q K^T : 32 rows x 64 keys per wave
    f32x4 S[2][4];
    for (int mi = 0; mi < 2; mi++)
      for (int ni = 0; ni < 4; ni++) S[mi][ni] = zero;
    for (int kh = 0; kh < 2; kh++) {
      bf16x8 bk[4];
      for (int ni = 0; ni < 4; ni++)
        bk[ni] = *(const bf16x8*)&Ks[(ni * 16 + ln) * 72 + kh * 32 + quad * 8];
      for (int mi = 0; mi < 2; mi++)
        for (int ni = 0; ni < 4; ni++)
          S[mi][ni] = __builtin_amdgcn_mfma_f32_16x16x32_bf16(qf[mi][kh], bk[ni],
                                                              S[mi][ni], 0, 0, 0);
    }

    // register online softmax (row = mi*16 + quad*4 + r, cols across ni,ln)
    for (int mi = 0; mi < 2; mi++) {
      for (int r = 0; r < 4; r++) {
        float rm = fmaxf(fmaxf(S[mi][0][r], S[mi][1][r]),
                         fmaxf(S[mi][2][r], S[mi][3][r]));
        rm = fmaxf(rm, __shfl_xor(rm, 1, 64));
        rm = fmaxf(rm, __shfl_xor(rm, 2, 64));
        rm = fmaxf(rm, __shfl_xor(rm, 4, 64));
        rm = fmaxf(rm, __shfl_xor(rm, 8, 64));
        float mo = mrow[mi][r];
        float mn = fmaxf(mo, rm);
        float al = __expf(mo - mn);
        mrow[mi][r] = mn;
        float rs = 0.0f;
        for (int ni = 0; ni < 4; ni++) {
          float e = __expf(S[mi][ni][r] - mn);
          S[mi][ni][r] = e;
          rs += e;
        }
        rs += __shfl_xor(rs, 1, 64);
        rs += __shfl_xor(rs, 2, 64);
        rs += __shfl_xor(rs, 4, 64);
        rs += __shfl_xor(rs, 8, 64);
        lrow[mi][r] = lrow[mi][r] * al + rs;
        for (int ni = 0; ni < 4; ni++) o_acc[mi][ni][r] *= al;
      }
    }

    // P (C-layout) -> LDS -> A-frags
    for (int mi = 0; mi < 2; mi++)
      for (int ni = 0; ni < 4; ni++)
        for (int r = 0; r < 4; r++)
          Pws[(mi * 16 + quad * 4 + r) * 68 + ni * 16 + ln] = f2bf(S[mi][ni][r]);
    __syncthreads();  // fence scalar ds_writes vs vector ds_reads

    for (int kh = 0; kh < 2; kh++) {
      U8 ap[2];
      for (int mi = 0; mi < 2; mi++) {
        ap[mi].h[0] = *(const ushortx4*)&Pws[(mi * 16 + ln) * 68 + kh * 32 + quad * 8];
        ap[mi].h[1] = *(const ushortx4*)&Pws[(mi * 16 + ln) * 68 + kh * 32 + quad * 8 + 4];
      }
      bf16x8 bv[4];
      for (int ni = 0; ni < 4; ni++)
        bv[ni] = *(const bf16x8*)&Vt[(ni * 16 + ln) * 72 + kh * 32 + quad * 8];
      for (int mi = 0; mi < 2; mi++)
        for (int ni = 0; ni < 4; ni++)
          o_acc[mi][ni] = __builtin_amdgcn_mfma_f32_16x16x32_bf16(ap[mi].b, bv[ni],
                                                                  o_acc[mi][ni], 0, 0, 0);
    }
  }

  // epilogue: normalize, stage to Pws, coalesced b128 stores
  __syncthreads();
  for (int mi = 0; mi < 2; mi++)
    for (int r = 0; r < 4; r++) {
      float inv = 1.0f / lrow[mi][r];
      for (int ni = 0; ni < 4; ni++)
        Pws[(mi * 16 + quad * 4 + r) * 68 + ni * 16 + ln] =
            f2bf(o_acc[mi][ni][r] * inv);
    }
  __syncthreads();
  for (int p = 0; p < 4; p++) {
    int rr = p * 8 + (lane >> 3);
    U8 u;
    u.h[0] = *(const ushortx4*)&Pws[rr * 68 + (lane & 7) * 8];
    u.h[1] = *(const ushortx4*)&Pws[rr * 68 + (lane & 7) * 8 + 4];
    *(ushortx8*)&o[(size_t)(qrow0 + w * 32 + rr) * 768 + h * 64 + (lane & 7) * 8] = u.u;
  }
}

// ---------------------------------------------------------------------------
extern "C" void kernel_launch(void* const* d_in, const int* in_sizes, int n_in,
                              void* d_out, int out_size, void* d_ws, size_t ws_size,
                              hipStream_t stream) {
  const float* hidden = (const float*)d_in[0];
  const float* ln1_g  = (const float*)d_in[1];
  const float* ln1_b  = (const float*)d_in[2];
  const float* w_qkv  = (const float*)d_in[3];
  const float* b_qkv  = (const float*)d_in[4];
  const float* w_attn = (const float*)d_in[5];
  const float* b_attn = (const float*)d_in[6];
  const float* ln2_g  = (const float*)d_in[7];
  const float* ln2_b  = (const float*)d_in[8];
  const float* w_in   = (const float*)d_in[9];
  const float* b_in   = (const float*)d_in[10];
  const float* w_out  = (const float*)d_in[11];
  const float* b_out  = (const float*)d_in[12];
  float* out = (float*)d_out;

  char* ws = (char*)d_ws;
  unsigned short* wqkvT  = (unsigned short*)(ws + 0);         // 2304x768 bf16
  unsigned short* wattnT = (unsigned short*)(ws + 3538944);   //  768x768
  unsigned short* winT   = (unsigned short*)(ws + 4718592);   // 3072x768
  unsigned short* woutT  = (unsigned short*)(ws + 9437184);   //  768x3072
  unsigned short* bufX   = (unsigned short*)(ws + 14155776);  // 8192x768 bf16
  unsigned short* bufBig = (unsigned short*)(ws + 26738688);  // 8192x3072 bf16
  // attention phase overlays inside bufBig (dead once gemm_ffn1 writes):
  unsigned short* bufQK  = bufBig;                            // 8192x1536 bf16
  unsigned short* v_t    = (unsigned short*)(ws + 26738688 + 25165824);  // 768x... V^T

  dim3 tb(32, 8);
  transpose_cast<<<dim3(2304 / 32, 768 / 32), tb, 0, stream>>>(w_qkv, wqkvT, 768, 2304);
  transpose_cast<<<dim3(768 / 32, 768 / 32), tb, 0, stream>>>(w_attn, wattnT, 768, 768);
  transpose_cast<<<dim3(3072 / 32, 768 / 32), tb, 0, stream>>>(w_in, winT, 768, 3072);
  transpose_cast<<<dim3(768 / 32, 3072 / 32), tb, 0, stream>>>(w_out, woutT, 3072, 768);

  ln_kernel<<<8192, 256, 0, stream>>>(hidden, ln1_g, ln1_b, bufX);
  gemm_qkv<<<dim3(18, 64), 256, 0, stream>>>(bufX, wqkvT, b_qkv, (void*)bufQK,
                                             v_t, 2304, 768);
  flash_attn<<<dim3(16, 48), 256, 0, stream>>>(bufQK, v_t, bufX);
  gemm_attnout<<<dim3(6, 64), 256, 0, stream>>>(bufX, wattnT, b_attn, hidden,
                                                (void*)out, 768, 768);
  ln_kernel<<<8192, 256, 0, stream>>>(out, ln2_g, ln2_b, bufX);
  gemm_ffn1<<<dim3(24, 64), 256, 0, stream>>>(bufX, winT, b_in, (void*)bufBig,
                                              3072, 768);
  gemm_ffn2<<<dim3(6, 64), 256, 0, stream>>>(bufBig, woutT, b_out, out,
                                             (void*)out, 768, 3072);
}

// Round 6
// 480.869 us; speedup vs baseline: 1.9703x; 1.1521x over previous
//
#include <hip/hip_runtime.h>

typedef __bf16 bf16_t;
typedef bf16_t bf16x8 __attribute__((ext_vector_type(8)));
typedef float f32x4 __attribute__((ext_vector_type(4)));
typedef unsigned short ushortx8 __attribute__((ext_vector_type(8)));
typedef unsigned short ushortx4 __attribute__((ext_vector_type(4)));
typedef short short4v __attribute__((ext_vector_type(4)));

union U8 { ushortx4 h[2]; bf16x8 b; ushortx8 u; };

__device__ __forceinline__ unsigned short f2bf(float f) {
  unsigned int u = __float_as_uint(f);
  u += 0x7fffu + ((u >> 16) & 1u);   // round-to-nearest-even
  return (unsigned short)(u >> 16);
}

// async global->LDS, 16B per lane; LDS dest is wave-uniform base + lane*16
__device__ __forceinline__ void gl_lds16(const unsigned short* g, unsigned short* l) {
  __builtin_amdgcn_global_load_lds((const __attribute__((address_space(1))) void*)g,
                                   (__attribute__((address_space(3))) void*)l,
                                   16, 0, 0);
}

// ---------------------------------------------------------------------------
// LayerNorm: fp32 [rows x 768] -> bf16 bits [rows x 768]
// ---------------------------------------------------------------------------
__global__ __launch_bounds__(256) void ln_kernel(const float* __restrict__ x,
                                                 const float* __restrict__ g,
                                                 const float* __restrict__ b,
                                                 unsigned short* __restrict__ out) {
  int row = blockIdx.x;
  int t = threadIdx.x;
  const float* xr = x + (size_t)row * 768;
  float v0 = xr[t], v1 = xr[t + 256], v2 = xr[t + 512];
  __shared__ float red[4];
  float s = v0 + v1 + v2;
  for (int o = 32; o > 0; o >>= 1) s += __shfl_down(s, o, 64);
  if ((t & 63) == 0) red[t >> 6] = s;
  __syncthreads();
  float mu = (red[0] + red[1] + red[2] + red[3]) * (1.0f / 768.0f);
  __syncthreads();
  float d0 = v0 - mu, d1 = v1 - mu, d2 = v2 - mu;
  s = d0 * d0 + d1 * d1 + d2 * d2;
  for (int o = 32; o > 0; o >>= 1) s += __shfl_down(s, o, 64);
  if ((t & 63) == 0) red[t >> 6] = s;
  __syncthreads();
  float var = (red[0] + red[1] + red[2] + red[3]) * (1.0f / 768.0f);
  float rs = rsqrtf(var + 1e-6f);
  unsigned short* orow = out + (size_t)row * 768;
  orow[t]       = f2bf(d0 * rs * g[t]       + b[t]);
  orow[t + 256] = f2bf(d1 * rs * g[t + 256] + b[t + 256]);
  orow[t + 512] = f2bf(d2 * rs * g[t + 512] + b[t + 512]);
}

// ---------------------------------------------------------------------------
// Transpose+cast: W fp32 [K x N] -> WT bf16 bits [N x K]
// ---------------------------------------------------------------------------
__global__ __launch_bounds__(256) void transpose_cast(const float* __restrict__ W,
                                                      unsigned short* __restrict__ WT,
                                                      int K, int N) {
  __shared__ float tile[32][33];
  int n0 = blockIdx.x * 32, k0 = blockIdx.y * 32;
  int tx = threadIdx.x, ty = threadIdx.y;
  for (int i = 0; i < 4; i++)
    tile[ty + i * 8][tx] = W[(size_t)(k0 + ty + i * 8) * N + n0 + tx];
  __syncthreads();
  for (int i = 0; i < 4; i++)
    WT[(size_t)(n0 + ty + i * 8) * K + k0 + tx] = f2bf(tile[tx][ty + i * 8]);
}

// ---------------------------------------------------------------------------
// GEMM body: C[M,N] = epi(A[M,K]_bf16 @ BT[N,K]_bf16^T + bias [+ resid])
// 128x128 tile, BK=32, 4 waves x (4x4) 16x16x32 mfma.
// Staging: global_load_lds width-16 (m97 ladder; exonerated by round-3
// bisect — the round-2 failure was the unfenced epilogue, fixed round 4).
// EPI 0: QKV. Q/K cols (<1536): bf16 out stride os (=1536), q cols scaled
//        0.125. V cols (>=1536): written TRANSPOSED to vt[b*768+(h*64+d)][s].
// EPI 1: bf16 out, exact GELU, stride N.
// EPI 2: fp32 out, + resid, direct scalar stores.
// bf16 epilogues round-trip through LDS with barrier fences (TBAA hazard:
// unfenced scalar-write -> vector-read miscompiles).
// ---------------------------------------------------------------------------
template <int EPI>
__device__ __forceinline__ void gemm_body(const unsigned short* __restrict__ A,
                                          const unsigned short* __restrict__ BT,
                                          const float* __restrict__ bias,
                                          const float* resid,
                                          void* out, unsigned short* vt, int os,
                                          int N, int K) {
  __shared__ __align__(16) unsigned short smem[128 * 64];  // 16 KB: As | Bs
  unsigned short* As = smem;
  unsigned short* Bs = smem + 4096;

  int t = threadIdx.x;
  int w = t >> 6, lane = t & 63, ln = lane & 15, quad = lane >> 4;
  int wm = w & 1, wn = w >> 1;
  int m0 = blockIdx.y * 128, n0 = blockIdx.x * 128;

  // DMA staging: wave w covers 16 rows (4 lanes x 16B per 64B row)
  int srow = w * 16 + (lane >> 2);
  int scol = (lane & 3) * 8;
  const unsigned short* gA0 = A + (size_t)(m0 + srow) * K + scol;
  const unsigned short* gA1 = gA0 + (size_t)64 * K;
  const unsigned short* gB0 = BT + (size_t)(n0 + srow) * K + scol;
  const unsigned short* gB1 = gB0 + (size_t)64 * K;
  unsigned short* dA0 = As + w * 512;          // wave-uniform LDS bases
  unsigned short* dA1 = As + 2048 + w * 512;
  unsigned short* dB0 = Bs + w * 512;
  unsigned short* dB1 = Bs + 2048 + w * 512;

  f32x4 acc[4][4];
  f32x4 zero = {0.f, 0.f, 0.f, 0.f};
  for (int mi = 0; mi < 4; mi++)
    for (int ni = 0; ni < 4; ni++) acc[mi][ni] = zero;

  int nk = K >> 5;
  for (int kt = 0; kt < nk; kt++) {
    __syncthreads();  // previous iter's ds_reads done before LDS overwrite
    gl_lds16(gA0, dA0);
    gl_lds16(gA1, dA1);
    gl_lds16(gB0, dB0);
    gl_lds16(gB1, dB1);
    gA0 += 32; gA1 += 32; gB0 += 32; gB1 += 32;
    __syncthreads();  // vmcnt(0) drain: LDS tiles ready
    bf16x8 af[4], bf[4];
    for (int mi = 0; mi < 4; mi++)
      af[mi] = *(const bf16x8*)&As[(wm * 64 + mi * 16 + ln) * 32 + quad * 8];
    for (int ni = 0; ni < 4; ni++)
      bf[ni] = *(const bf16x8*)&Bs[(wn * 64 + ni * 16 + ln) * 32 + quad * 8];
    for (int mi = 0; mi < 4; mi++)
      for (int ni = 0; ni < 4; ni++)
        acc[mi][ni] = __builtin_amdgcn_mfma_f32_16x16x32_bf16(af[mi], bf[ni],
                                                              acc[mi][ni], 0, 0, 0);
  }

  if (EPI == 2) {
    float* outp = (float*)out;
    for (int mi = 0; mi < 4; mi++) {
      for (int ni = 0; ni < 4; ni++) {
        int col = n0 + wn * 64 + ni * 16 + ln;
        float bv = bias[col];
        for (int r = 0; r < 4; r++) {
          int row = m0 + wm * 64 + mi * 16 + quad * 4 + r;
          float v = acc[mi][ni][r] + bv;
          v += resid[(size_t)row * N + col];
          outp[(size_t)row * N + col] = v;
        }
      }
    }
  } else {
    __syncthreads();  // all waves done with As/Bs; reuse as epilogue scratch
    unsigned short* Cs16 = smem + w * 1024;  // 2 KB per wave (16 rows x 64)
    unsigned short* outp = (unsigned short*)out;
    for (int mi = 0; mi < 4; mi++) {
      for (int ni = 0; ni < 4; ni++) {
        int col = n0 + wn * 64 + ni * 16 + ln;
        float bv = bias[col];
        for (int r = 0; r < 4; r++) {
          float v = acc[mi][ni][r] + bv;
          if (EPI == 0) {
            if (col < 768) v *= 0.125f;  // q * hd^-0.5
          } else {
            v = 0.5f * v * (1.0f + erff(v * 0.70710678118654752f));
          }
          Cs16[(quad * 4 + r) * 64 + ni * 16 + ln] = f2bf(v);
        }
      }
      __syncthreads();  // fence: scalar ds_writes visible before reads
      if (EPI == 0 && n0 >= 1536) {
        // V^T path: lane <-> column; 16 s-values contiguous per store
        int c = n0 - 1536 + wn * 64 + lane;  // h*64+d, 0..767
        int s0 = m0 + wm * 64 + mi * 16;
        int bb = s0 >> 11, sl = s0 & 2047;
        ushortx8 lo, hi;
        for (int r = 0; r < 8; r++) lo[r] = Cs16[r * 64 + lane];
        for (int r = 0; r < 8; r++) hi[r] = Cs16[(8 + r) * 64 + lane];
        size_t vbase = ((size_t)(bb * 768 + c)) * 2048 + sl;
        *(ushortx8*)&vt[vbase] = lo;
        *(ushortx8*)&vt[vbase + 8] = hi;
      } else {
        int OS = (EPI == 0) ? os : N;
        for (int j = 0; j < 2; j++) {
          int rrow = j * 8 + (lane >> 3);
          int ch = (lane & 7) * 8;
          ushortx8 pv = *(const ushortx8*)&Cs16[rrow * 64 + ch];
          *(ushortx8*)&outp[(size_t)(m0 + wm * 64 + mi * 16 + rrow) * OS +
                            n0 + wn * 64 + ch] = pv;
        }
      }
      __syncthreads();  // reads done before next slab overwrites scratch
    }
  }
}

__global__ __launch_bounds__(256) void gemm_qkv(const unsigned short* A,
    const unsigned short* BT, const float* bias, void* out, unsigned short* vt,
    int N, int K) {
  gemm_body<0>(A, BT, bias, nullptr, out, vt, 1536, N, K);
}
__global__ __launch_bounds__(256) void gemm_attnout(const unsigned short* A,
    const unsigned short* BT, const float* bias, const float* resid, void* out,
    int N, int K) {
  gemm_body<2>(A, BT, bias, resid, out, nullptr, N, N, K);
}
__global__ __launch_bounds__(256) void gemm_ffn1(const unsigned short* A,
    const unsigned short* BT, const float* bias, void* out, int N, int K) {
  gemm_body<1>(A, BT, bias, nullptr, out, nullptr, N, N, K);
}
__global__ __launch_bounds__(256) void gemm_ffn2(const unsigned short* A,
    const unsigned short* BT, const float* bias, const float* resid, void* out,
    int N, int K) {
  gemm_body<2>(A, BT, bias, resid, out, nullptr, N, N, K);
}

// ---------------------------------------------------------------------------
// Flash attention v3 — operand-swap: compute S^T = K·Q^T so softmax reduces
// over {in-lane, quad} (2 shuffles) and P^T (C-layout, k=quad*4+r) feeds the
// 16x16x16 PV MFMA as B operand DIRECTLY from registers (no LDS round-trip).
// O^T accumulates in C-layout (row=d, col=q); one LDS transpose at epilogue.
// qk: bf16 [8192 x 1536] (q|k, q pre-scaled); v_t: bf16 [48*64 x 2048] (V^T).
// Block: 128 q x (b,h); wave owns 32 q x 64 keys/iter.
// ---------------------------------------------------------------------------
__global__ __launch_bounds__(256, 3) void flash_attn(
    const unsigned short* __restrict__ qk, const unsigned short* __restrict__ v_t,
    unsigned short* __restrict__ o) {
  int qt = blockIdx.x;  // 0..15
  int bh = blockIdx.y;  // 0..47
  int b = bh / 12, h = bh % 12;
  int t = threadIdx.x;
  int w = t >> 6, lane = t & 63, ln = lane & 15, quad = lane >> 4;

  __shared__ __align__(16) unsigned short smem[9216];  // 18.4 KB
  unsigned short* Ks = smem;          // [64 keys][72] (cols = d)
  unsigned short* Vt = smem + 4608;   // [64 d][72]   (cols = key)
  unsigned short* Osm = smem + w * 2304;  // epilogue overlay [32 q][72] per wave

  int qrow0 = b * 2048 + qt * 128;

  // Q as B-operand frags (k=d, n=q), loaded once
  bf16x8 qf[2][2];
  for (int qi = 0; qi < 2; qi++)
    for (int kh = 0; kh < 2; kh++)
      qf[qi][kh] = *(const bf16x8*)&qk[(size_t)(qrow0 + w * 32 + qi * 16 + ln) * 1536 +
                                      h * 64 + kh * 32 + quad * 8];

  f32x4 zero = {0.f, 0.f, 0.f, 0.f};
  f32x4 o_acc[4][2];  // [df][qi]: O^T frag, row=d-part, col=q-part
  for (int df = 0; df < 4; df++)
    for (int qi = 0; qi < 2; qi++) o_acc[df][qi] = zero;
  float mrow[2] = {-1e30f, -1e30f}, lrow[2] = {0.0f, 0.0f};

  int sr = t >> 3, sc = (t & 7) * 8;  // staging: 32 rows x 8 chunks per pass
  for (int kt = 0; kt < 32; kt++) {
    int krow0 = b * 2048 + kt * 64;
    ushortx8 kreg[2], vreg[2];
    for (int p = 0; p < 2; p++) {
      int r = p * 32 + sr;
      kreg[p] = *(const ushortx8*)&qk[(size_t)(krow0 + r) * 1536 + 768 + h * 64 + sc];
      vreg[p] = *(const ushortx8*)&v_t[(size_t)(bh * 64 + r) * 2048 + kt * 64 + sc];
    }
    __syncthreads();  // prev iter's frag reads done
    for (int p = 0; p < 2; p++) {
      int r = p * 32 + sr;
      *(ushortx8*)&Ks[r * 72 + sc] = kreg[p];
      *(ushortx8*)&Vt[r * 72 + sc] = vreg[p];
    }
    __syncthreads();

    // S^T = K Q^T : [64 keys x 32 q] per wave (A=K frag, B=Q frag)
    f32x4 ST[4][2];
    for (int kf = 0; kf < 4; kf++)
      for (int qi = 0; qi < 2; qi++) ST[kf][qi] = zero;
    for (int kh = 0; kh < 2; kh++) {
      bf16x8 kA[4];
      for (int kf = 0; kf < 4; kf++)
        kA[kf] = *(const bf16x8*)&Ks[(kf * 16 + ln) * 72 + kh * 32 + quad * 8];
      for (int kf = 0; kf < 4; kf++)
        for (int qi = 0; qi < 2; qi++)
          ST[kf][qi] = __builtin_amdgcn_mfma_f32_16x16x32_bf16(kA[kf], qf[qi][kh],
                                                               ST[kf][qi], 0, 0, 0);
    }

    // online softmax per q-column (col=ln): 16 in-lane + 2 shuffles
    for (int qi = 0; qi < 2; qi++) {
      float rm = -1e30f;
      for (int kf = 0; kf < 4; kf++)
        for (int r = 0; r < 4; r++) rm = fmaxf(rm, ST[kf][qi][r]);
      rm = fmaxf(rm, __shfl_xor(rm, 16, 64));
      rm = fmaxf(rm, __shfl_xor(rm, 32, 64));
      float mo = mrow[qi];
      float mn = fmaxf(mo, rm);
      float al = __expf(mo - mn);
      mrow[qi] = mn;
      float rs = 0.0f;
      for (int kf = 0; kf < 4; kf++)
        for (int r = 0; r < 4; r++) {
          float e = __expf(ST[kf][qi][r] - mn);
          ST[kf][qi][r] = e;
          rs += e;
        }
      rs += __shfl_xor(rs, 16, 64);
      rs += __shfl_xor(rs, 32, 64);
      lrow[qi] = lrow[qi] * al + rs;
      for (int df = 0; df < 4; df++)
        for (int r = 0; r < 4; r++) o_acc[df][qi][r] *= al;
    }

    // O^T += V^T P^T : P^T C-layout (k=quad*4+r) is the 16x16x16 B-layout
    short4v pT[4][2];
    for (int kf = 0; kf < 4; kf++)
      for (int qi = 0; qi < 2; qi++)
        for (int r = 0; r < 4; r++)
          pT[kf][qi][r] = (short)f2bf(ST[kf][qi][r]);
    for (int kf = 0; kf < 4; kf++) {
      short4v vA[4];
      for (int df = 0; df < 4; df++)
        vA[df] = *(const short4v*)&Vt[(df * 16 + ln) * 72 + kf * 16 + quad * 4];
      for (int df = 0; df < 4; df++)
        for (int qi = 0; qi < 2; qi++)
          o_acc[df][qi] = __builtin_amdgcn_mfma_f32_16x16x16bf16_1k(
              vA[df], pT[kf][qi], o_acc[df][qi], 0, 0, 0);
    }
  }

  // epilogue: normalize (per q col), transpose via LDS, coalesced b128 stores
  __syncthreads();  // all frag reads done; overlay Ks/Vt with Osm
  for (int qi = 0; qi < 2; qi++) {
    float inv = 1.0f / lrow[qi];
    for (int df = 0; df < 4; df++)
      for (int r = 0; r < 4; r++)
        Osm[(qi * 16 + ln) * 72 + df * 16 + quad * 4 + r] =
            f2bf(o_acc[df][qi][r] * inv);
  }
  __syncthreads();  // fence scalar ds_writes vs vector ds_reads
  for (int p = 0; p < 4; p++) {
    int rr = p * 8 + (lane >> 3);
    int ch = (lane & 7) * 8;
    ushortx8 u = *(const ushortx8*)&Osm[rr * 72 + ch];
    *(ushortx8*)&o[(size_t)(qrow0 + w * 32 + rr) * 768 + h * 64 + ch] = u;
  }
}

// ---------------------------------------------------------------------------
extern "C" void kernel_launch(void* const* d_in, const int* in_sizes, int n_in,
                              void* d_out, int out_size, void* d_ws, size_t ws_size,
                              hipStream_t stream) {
  const float* hidden = (const float*)d_in[0];
  const float* ln1_g  = (const float*)d_in[1];
  const float* ln1_b  = (const float*)d_in[2];
  const float* w_qkv  = (const float*)d_in[3];
  const float* b_qkv  = (const float*)d_in[4];
  const float* w_attn = (const float*)d_in[5];
  const float* b_attn = (const float*)d_in[6];
  const float* ln2_g  = (const float*)d_in[7];
  const float* ln2_b  = (const float*)d_in[8];
  const float* w_in   = (const float*)d_in[9];
  const float* b_in   = (const float*)d_in[10];
  const float* w_out  = (const float*)d_in[11];
  const float* b_out  = (const float*)d_in[12];
  float* out = (float*)d_out;

  char* ws = (char*)d_ws;
  unsigned short* wqkvT  = (unsigned short*)(ws + 0);         // 2304x768 bf16
  unsigned short* wattnT = (unsigned short*)(ws + 3538944);   //  768x768
  unsigned short* winT   = (unsigned short*)(ws + 4718592);   // 3072x768
  unsigned short* woutT  = (unsigned short*)(ws + 9437184);   //  768x3072
  unsigned short* bufX   = (unsigned short*)(ws + 14155776);  // 8192x768 bf16
  unsigned short* bufBig = (unsigned short*)(ws + 26738688);  // 8192x3072 bf16
  unsigned short* bufQK  = bufBig;                            // 8192x1536 bf16
  unsigned short* v_t    = (unsigned short*)(ws + 26738688 + 25165824);  // V^T

  dim3 tb(32, 8);
  transpose_cast<<<dim3(2304 / 32, 768 / 32), tb, 0, stream>>>(w_qkv, wqkvT, 768, 2304);
  transpose_cast<<<dim3(768 / 32, 768 / 32), tb, 0, stream>>>(w_attn, wattnT, 768, 768);
  transpose_cast<<<dim3(3072 / 32, 768 / 32), tb, 0, stream>>>(w_in, winT, 768, 3072);
  transpose_cast<<<dim3(768 / 32, 3072 / 32), tb, 0, stream>>>(w_out, woutT, 3072, 768);

  ln_kernel<<<8192, 256, 0, stream>>>(hidden, ln1_g, ln1_b, bufX);
  gemm_qkv<<<dim3(18, 64), 256, 0, stream>>>(bufX, wqkvT, b_qkv, (void*)bufQK,
                                             v_t, 2304, 768);
  flash_attn<<<dim3(16, 48), 256, 0, stream>>>(bufQK, v_t, bufX);
  gemm_attnout<<<dim3(6, 64), 256, 0, stream>>>(bufX, wattnT, b_attn, hidden,
                                                (void*)out, 768, 768);
  ln_kernel<<<8192, 256, 0, stream>>>(out, ln2_g, ln2_b, bufX);
  gemm_ffn1<<<dim3(24, 64), 256, 0, stream>>>(bufX, winT, b_in, (void*)bufBig,
                                              3072, 768);
  gemm_ffn2<<<dim3(6, 64), 256, 0, stream>>>(bufBig, woutT, b_out, out,
                                             (void*)out, 768, 3072);
}